// Round 1
// baseline (45629.871 us; speedup 1.0000x reference)
//
#include <hip/hip_runtime.h>
#include <hip/hip_cooperative_groups.h>

namespace cg = cooperative_groups;

typedef _Float16 half8 __attribute__((ext_vector_type(8)));
typedef float f32x4 __attribute__((ext_vector_type(4)));

constexpr int BB = 128;   // batch
constexpr int SS = 512;   // seq len
constexpr int II = 512;   // input dim
constexpr int HH = 1024;  // hidden dim

constexpr int JSL = 16;          // output-j's per WG (both layers)
constexpr int K0  = II + HH;     // layer-0 reduction: x(512) + h1(1024) = 1536
constexpr int K1  = HH + HH;     // layer-1 reduction: h1 + h2 = 2048
constexpr int LDS_ELEMS = JSL * K0 + JSL * K1;  // 57344 fp16 = 112 KiB

// Grid: 256 WGs = 64 j-slices x 4 b-slices. 4 waves/WG:
//   wave 0/1 : layer-0, b-half 0/1   (K=1536: x then h1_prev)
//   wave 2/3 : layer-1, b-half 0/1   (K=2048: h1_prev then h2_prev)
// Weights fp32->fp16 into LDS once, XOR-swizzled (elem ^= (j&7)<<3) so the
// stride-K ds_read_b128 of B-fragments is ~conflict-free (2-way).
__global__ __launch_bounds__(256) void rnn_fused(
    const float* __restrict__ x,
    const float* __restrict__ Wih0, const float* __restrict__ Whh0,
    const float* __restrict__ bi0,  const float* __restrict__ bh0,
    const float* __restrict__ Wih1, const float* __restrict__ Whh1,
    const float* __restrict__ bi1,  const float* __restrict__ bh1,
    const float* __restrict__ W2,   const float* __restrict__ b2,
    _Float16* __restrict__ ws, float* __restrict__ out)
{
  extern __shared__ _Float16 lds[];
  const int tid = threadIdx.x;
  const int wg  = blockIdx.x;
  const int js  = wg & 63;       // 64 j-slices
  const int bs  = wg >> 6;       // 4 b-slices
  const int j0  = js * JSL;
  const int Bb  = bs * 32;

  // ---- one-time: stage this WG's weight slices into LDS (fp16, swizzled) ----
  for (int e = tid; e < JSL * (K0 + K1); e += 256) {
    int jj = e / (K0 + K1);
    int kk = e - jj * (K0 + K1);
    float v; int dst;
    if (kk < K0) {
      v = (kk < II) ? Wih0[(size_t)(j0 + jj) * II + kk]
                    : Whh0[(size_t)(j0 + jj) * HH + (kk - II)];
      dst = jj * K0 + (kk ^ ((jj & 7) << 3));
    } else {
      int k2 = kk - K0;
      v = (k2 < HH) ? Wih1[(size_t)(j0 + jj) * HH + k2]
                    : Whh1[(size_t)(j0 + jj) * HH + (k2 - HH)];
      dst = JSL * K0 + jj * K1 + (k2 ^ ((jj & 7) << 3));
    }
    lds[dst] = (_Float16)v;
  }
  __syncthreads();

  const int wid   = tid >> 6;
  const int ln    = tid & 63;
  const int lj    = ln & 15;          // B-frag col (j) / A-frag row (b) lane index
  const int lk    = (ln >> 4) * 8;    // k sub-offset per lane-quarter
  const int layer = wid >> 1;
  const int wb    = Bb + (wid & 1) * 16;  // wave's batch-row base
  const int arow  = wb + lj;              // this lane's A-fragment row (batch idx)
  const int swz   = (lj & 7) << 3;

  const float bias_f = (layer == 0) ? (bi0[j0 + lj] + bh0[j0 + lj])
                                    : (bi1[j0 + lj] + bh1[j0 + lj]);

  const _Float16* w0row = lds + lj * K0;
  const _Float16* w1row = lds + JSL * K0 + lj * K1;

  _Float16* h1A = ws;
  _Float16* h1B = ws + (size_t)BB * HH;
  _Float16* h2A = ws + (size_t)2 * BB * HH;
  _Float16* h2B = ws + (size_t)3 * BB * HH;
  _Float16 *h1p = h1A, *h1c = h1B, *h2p = h2A, *h2c = h2B;

  cg::grid_group grid = cg::this_grid();

  // Pipelined scan: iteration t computes h1[t] (layer 0) and h2[t-1] (layer 1).
  for (int t = 0; t <= SS; ++t) {
    if (layer == 0) {
      if (t < SS) {
        f32x4 acc = {0.f, 0.f, 0.f, 0.f};
        const float* xrow = x + ((size_t)arow * SS + t) * II;
        #pragma unroll 8
        for (int kt = 0; kt < II / 32; ++kt) {
          int k = kt * 32 + lk;
          f32x4 u = *(const f32x4*)(xrow + k);
          f32x4 v = *(const f32x4*)(xrow + k + 4);
          half8 a;
          a[0] = (_Float16)u[0]; a[1] = (_Float16)u[1];
          a[2] = (_Float16)u[2]; a[3] = (_Float16)u[3];
          a[4] = (_Float16)v[0]; a[5] = (_Float16)v[1];
          a[6] = (_Float16)v[2]; a[7] = (_Float16)v[3];
          half8 b = *(const half8*)(w0row + (k ^ swz));
          acc = __builtin_amdgcn_mfma_f32_16x16x32_f16(a, b, acc, 0, 0, 0);
        }
        if (t > 0) {
          const _Float16* hrow = h1p + (size_t)arow * HH;
          #pragma unroll 8
          for (int kt = 0; kt < HH / 32; ++kt) {
            int k = kt * 32 + lk;
            half8 a = *(const half8*)(hrow + k);
            half8 b = *(const half8*)(w0row + ((II + k) ^ swz));
            acc = __builtin_amdgcn_mfma_f32_16x16x32_f16(a, b, acc, 0, 0, 0);
          }
        }
        #pragma unroll
        for (int i = 0; i < 4; ++i) {
          int r = wb + (ln >> 4) * 4 + i;
          float pre = acc[i] + bias_f;
          h1c[(size_t)r * HH + j0 + lj] = (_Float16)tanhf(pre);
        }
      }
    } else {
      if (t >= 1) {
        f32x4 acc = {0.f, 0.f, 0.f, 0.f};
        const _Float16* hrow = h1p + (size_t)arow * HH;
        #pragma unroll 8
        for (int kt = 0; kt < HH / 32; ++kt) {
          int k = kt * 32 + lk;
          half8 a = *(const half8*)(hrow + k);
          half8 b = *(const half8*)(w1row + (k ^ swz));
          acc = __builtin_amdgcn_mfma_f32_16x16x32_f16(a, b, acc, 0, 0, 0);
        }
        if (t >= 2) {
          const _Float16* h2row = h2p + (size_t)arow * HH;
          #pragma unroll 8
          for (int kt = 0; kt < HH / 32; ++kt) {
            int k = kt * 32 + lk;
            half8 a = *(const half8*)(h2row + k);
            half8 b = *(const half8*)(w1row + ((HH + k) ^ swz));
            acc = __builtin_amdgcn_mfma_f32_16x16x32_f16(a, b, acc, 0, 0, 0);
          }
        }
        #pragma unroll
        for (int i = 0; i < 4; ++i) {
          int r = wb + (ln >> 4) * 4 + i;
          float pre = acc[i] + bias_f;
          h2c[(size_t)r * HH + j0 + lj] = (_Float16)tanhf(pre);
        }
      }
    }
    __threadfence();   // release our h-writes device-wide
    grid.sync();
    __threadfence();   // acquire: don't read stale L2 after barrier
    _Float16* tt = h1p; h1p = h1c; h1c = tt;
    tt = h2p; h2p = h2c; h2c = tt;
  }

  // ---- FC head: logits = relu(h2[S-1] @ W2^T + b2), done by WG 0 ----
  if (wg == 0) {
    const int b = tid >> 1, c = tid & 1;
    const _Float16* hrow = h2p + (size_t)b * HH;
    const float* wr = W2 + (size_t)c * HH;
    float sum = b2[c];
    #pragma unroll 4
    for (int k = 0; k < HH; k += 8) {
      half8 hv = *(const half8*)(hrow + k);
      #pragma unroll
      for (int i = 0; i < 8; ++i) sum += (float)hv[i] * wr[k + i];
    }
    out[b * 2 + c] = fmaxf(sum, 0.f);
  }
}

extern "C" void kernel_launch(void* const* d_in, const int* in_sizes, int n_in,
                              void* d_out, int out_size, void* d_ws, size_t ws_size,
                              hipStream_t stream) {
  const float* x    = (const float*)d_in[0];
  // d_in[1] = mask (unused by the model)
  const float* Wih0 = (const float*)d_in[2];
  const float* Whh0 = (const float*)d_in[3];
  const float* bi0  = (const float*)d_in[4];
  const float* bh0  = (const float*)d_in[5];
  const float* Wih1 = (const float*)d_in[6];
  const float* Whh1 = (const float*)d_in[7];
  const float* bi1  = (const float*)d_in[8];
  const float* bh1  = (const float*)d_in[9];
  const float* W2   = (const float*)d_in[10];
  const float* b2   = (const float*)d_in[11];
  _Float16* ws = (_Float16*)d_ws;
  float* out   = (float*)d_out;

  const unsigned lds_bytes = (unsigned)(LDS_ELEMS * sizeof(_Float16));  // 112 KiB
  (void)hipFuncSetAttribute((const void*)rnn_fused,
                            hipFuncAttributeMaxDynamicSharedMemorySize,
                            (int)lds_bytes);

  void* args[] = { (void*)&x,
                   (void*)&Wih0, (void*)&Whh0, (void*)&bi0, (void*)&bh0,
                   (void*)&Wih1, (void*)&Whh1, (void*)&bi1, (void*)&bh1,
                   (void*)&W2,   (void*)&b2,   (void*)&ws,  (void*)&out };
  (void)hipLaunchCooperativeKernel((const void*)rnn_fused,
                                   dim3(256), dim3(256),
                                   args, lds_bytes, stream);
}

// Round 3
// 10708.820 us; speedup vs baseline: 4.2610x; 4.2610x over previous
//
#include <hip/hip_runtime.h>

typedef _Float16 half8 __attribute__((ext_vector_type(8)));
typedef float f32x4 __attribute__((ext_vector_type(4)));

constexpr int BB = 128;   // batch
constexpr int SS = 512;   // seq len
constexpr int II = 512;   // input dim
constexpr int HH = 1024;  // hidden dim

constexpr int JSL = 16;          // output-j's per WG (both layers)
constexpr int K0  = II + HH;     // layer-0 reduction: x(512) + h1(1024)
constexpr int K1  = HH + HH;     // layer-1 reduction: h1 + h2
constexpr int LDS_ELEMS = JSL * K0 + JSL * K1;   // 57344 fp16 = 112 KiB

constexpr size_t H_BYTES = (size_t)BB * HH * sizeof(_Float16);  // 256 KiB
constexpr size_t CNT_OFF = 4 * H_BYTES;                          // 1 MiB

__device__ inline float fast_tanh(float x) {
  float e = __expf(2.f * x);          // saturates to +-1 correctly at |x| large
  return 1.f - 2.f / (e + 1.f);
}

// Grid: 256 WGs. bs = wg&3 (so each XCD, under wg%8 round-robin, hosts ONE
// batch-slice -> per-step LLC->L2 h fetch is deduped across the XCD's 32 WGs),
// js = wg>>2 (64 j-slices). 4 waves/WG:
//   wave 0/1 : layer-0, b-half 0/1 ; wave 2/3 : layer-1, b-half 0/1
// Weights fp16 in LDS (XOR-swizzled). h1/h2 ping-pong in d_ws with ORDINARY
// cached loads/stores; cross-XCD visibility is provided per step by
//   release: __syncthreads -> leader fetch_add(RELEASE, agent)  [wbl2 sc1]
//   acquire: relaxed spin -> fence(ACQUIRE, agent)              [buffer_inv sc1]
__global__ __launch_bounds__(256, 1) void rnn_fused(
    const float* __restrict__ x,
    const float* __restrict__ Wih0, const float* __restrict__ Whh0,
    const float* __restrict__ bi0,  const float* __restrict__ bh0,
    const float* __restrict__ Wih1, const float* __restrict__ Whh1,
    const float* __restrict__ bi1,  const float* __restrict__ bh1,
    const float* __restrict__ W2,   const float* __restrict__ b2,
    _Float16* __restrict__ ws, unsigned* __restrict__ cnts,
    float* __restrict__ out)
{
  extern __shared__ _Float16 lds[];
  const int tid = threadIdx.x;
  const int wg  = blockIdx.x;
  const int bs  = wg & 3;        // batch-slice: constant per XCD under %8 RR
  const int js  = wg >> 2;       // 64 j-slices
  const int j0  = js * JSL;
  const int Bb  = bs * 32;

  // ---- one-time: stage weight slices into LDS (fp16, swizzled) ----
  for (int e = tid; e < JSL * (K0 + K1); e += 256) {
    int jj = e / (K0 + K1);
    int kk = e - jj * (K0 + K1);
    float v; int dst;
    if (kk < K0) {
      v = (kk < II) ? Wih0[(size_t)(j0 + jj) * II + kk]
                    : Whh0[(size_t)(j0 + jj) * HH + (kk - II)];
      dst = jj * K0 + (kk ^ ((jj & 7) << 3));
    } else {
      int k2 = kk - K0;
      v = (k2 < HH) ? Wih1[(size_t)(j0 + jj) * HH + k2]
                    : Whh1[(size_t)(j0 + jj) * HH + (k2 - HH)];
      dst = JSL * K0 + jj * K1 + (k2 ^ ((jj & 7) << 3));
    }
    lds[dst] = (_Float16)v;
  }
  __syncthreads();

  const int wid   = tid >> 6;
  const int ln    = tid & 63;
  const int lj    = ln & 15;
  const int lk    = (ln >> 4) * 8;
  const int layer = wid >> 1;
  const int wb    = Bb + (wid & 1) * 16;
  const int arow  = wb + lj;
  const int swz   = (lj & 7) << 3;

  const float bias_f = (layer == 0) ? (bi0[j0 + lj] + bh0[j0 + lj])
                                    : (bi1[j0 + lj] + bh1[j0 + lj]);

  const _Float16* w0row = lds + lj * K0;
  const _Float16* w1row = lds + JSL * K0 + lj * K1;

  _Float16* h1A = ws;
  _Float16* h1B = ws + (size_t)BB * HH;
  _Float16* h2A = ws + (size_t)2 * BB * HH;
  _Float16* h2B = ws + (size_t)3 * BB * HH;
  _Float16 *h1p = h1A, *h1c = h1B, *h2p = h2A, *h2c = h2B;

  unsigned* cnt_d = cnts + bs * 64;   // 256B-separated domain counters
  unsigned* cnt_f = cnts + 1024;      // final join counter
  unsigned tgt = 0;

  // x-projection for t=0 (no h dependency)
  f32x4 accx = {0.f, 0.f, 0.f, 0.f};
  if (layer == 0) {
    const float* xrow = x + ((size_t)arow * SS + 0) * II;
    #pragma unroll 8
    for (int kt = 0; kt < II / 32; ++kt) {
      int k = kt * 32 + lk;
      f32x4 u = *(const f32x4*)(xrow + k);
      f32x4 v = *(const f32x4*)(xrow + k + 4);
      half8 a;
      a[0]=(_Float16)u[0]; a[1]=(_Float16)u[1]; a[2]=(_Float16)u[2]; a[3]=(_Float16)u[3];
      a[4]=(_Float16)v[0]; a[5]=(_Float16)v[1]; a[6]=(_Float16)v[2]; a[7]=(_Float16)v[3];
      half8 b = *(const half8*)(w0row + (k ^ swz));
      accx = __builtin_amdgcn_mfma_f32_16x16x32_f16(a, b, accx, 0, 0, 0);
    }
  }

  // Pipelined scan: iteration t computes h1[t] (layer 0) and h2[t-1] (layer 1).
  for (int t = 0; t <= SS; ++t) {
    if (layer == 0) {
      if (t < SS) {
        f32x4 acc = accx;
        if (t > 0) {
          const _Float16* hrow = h1p + (size_t)arow * HH;
          half8 af[32];
          #pragma unroll
          for (int kt = 0; kt < 32; ++kt) af[kt] = *(const half8*)(hrow + kt * 32 + lk);
          #pragma unroll
          for (int kt = 0; kt < 32; ++kt) {
            int k = kt * 32 + lk;
            half8 b = *(const half8*)(w0row + ((II + k) ^ swz));
            acc = __builtin_amdgcn_mfma_f32_16x16x32_f16(af[kt], b, acc, 0, 0, 0);
          }
        }
        #pragma unroll
        for (int i = 0; i < 4; ++i) {
          int r = wb + (ln >> 4) * 4 + i;
          h1c[(size_t)r * HH + j0 + lj] = (_Float16)fast_tanh(acc[i] + bias_f);
        }
      }
    } else {
      if (t >= 1) {
        f32x4 acc = {0.f, 0.f, 0.f, 0.f};
        {
          const _Float16* hrow = h1p + (size_t)arow * HH;
          half8 af[32];
          #pragma unroll
          for (int kt = 0; kt < 32; ++kt) af[kt] = *(const half8*)(hrow + kt * 32 + lk);
          #pragma unroll
          for (int kt = 0; kt < 32; ++kt) {
            int k = kt * 32 + lk;
            half8 b = *(const half8*)(w1row + (k ^ swz));
            acc = __builtin_amdgcn_mfma_f32_16x16x32_f16(af[kt], b, acc, 0, 0, 0);
          }
        }
        if (t >= 2) {
          const _Float16* h2row = h2p + (size_t)arow * HH;
          half8 af[32];
          #pragma unroll
          for (int kt = 0; kt < 32; ++kt) af[kt] = *(const half8*)(h2row + kt * 32 + lk);
          #pragma unroll
          for (int kt = 0; kt < 32; ++kt) {
            int k = kt * 32 + lk;
            half8 b = *(const half8*)(w1row + ((HH + k) ^ swz));
            acc = __builtin_amdgcn_mfma_f32_16x16x32_f16(af[kt], b, acc, 0, 0, 0);
          }
        }
        #pragma unroll
        for (int i = 0; i < 4; ++i) {
          int r = wb + (ln >> 4) * 4 + i;
          h2c[(size_t)r * HH + j0 + lj] = (_Float16)fast_tanh(acc[i] + bias_f);
        }
      }
    }

    // ---- domain barrier (64 WGs sharing bs), release/acquire at agent scope ----
    __syncthreads();   // all waves' h stores drained to L2 before leader releases
    tgt += 64;
    if (tid == 0)      // RELEASE: waitcnt + buffer_wbl2 sc1 + atomic add @ LLC
      __hip_atomic_fetch_add(cnt_d, 1u, __ATOMIC_RELEASE, __HIP_MEMORY_SCOPE_AGENT);

    // overlap next step's x-projection with barrier skew (reads immutable x)
    if (layer == 0 && (t + 1) < SS) {
      const float* xrow = x + ((size_t)arow * SS + (t + 1)) * II;
      f32x4 a2 = {0.f, 0.f, 0.f, 0.f};
      #pragma unroll 8
      for (int kt = 0; kt < II / 32; ++kt) {
        int k = kt * 32 + lk;
        f32x4 u = *(const f32x4*)(xrow + k);
        f32x4 v = *(const f32x4*)(xrow + k + 4);
        half8 a;
        a[0]=(_Float16)u[0]; a[1]=(_Float16)u[1]; a[2]=(_Float16)u[2]; a[3]=(_Float16)u[3];
        a[4]=(_Float16)v[0]; a[5]=(_Float16)v[1]; a[6]=(_Float16)v[2]; a[7]=(_Float16)v[3];
        half8 b = *(const half8*)(w0row + (k ^ swz));
        a2 = __builtin_amdgcn_mfma_f32_16x16x32_f16(a, b, a2, 0, 0, 0);
      }
      accx = a2;
    }

    if (tid == 0) {
      while (__hip_atomic_load(cnt_d, __ATOMIC_RELAXED, __HIP_MEMORY_SCOPE_AGENT) < tgt)
        __builtin_amdgcn_s_sleep(1);
      __builtin_amdgcn_fence(__ATOMIC_ACQUIRE, "agent");  // buffer_inv sc1 (L1+L2)
    }
    __syncthreads();   // others' reads ordered after leader's invalidate

    _Float16* tt = h1p; h1p = h1c; h1c = tt;
    tt = h2p; h2p = h2c; h2c = tt;
  }

  // ---- final all-WG join (h2 data already released at last domain barrier) ----
  __syncthreads();
  if (tid == 0)
    __hip_atomic_fetch_add(cnt_f, 1u, __ATOMIC_RELAXED, __HIP_MEMORY_SCOPE_AGENT);

  if (wg == 0) {
    if (tid == 0) {
      while (__hip_atomic_load(cnt_f, __ATOMIC_RELAXED, __HIP_MEMORY_SCOPE_AGENT) < 256u)
        __builtin_amdgcn_s_sleep(1);
      __builtin_amdgcn_fence(__ATOMIC_ACQUIRE, "agent");
    }
    __syncthreads();
    const int b = tid >> 1, c = tid & 1;
    const _Float16* hrow = h2p + (size_t)b * HH;
    const float* wr = W2 + (size_t)c * HH;
    float sum = b2[c];
    #pragma unroll 4
    for (int k = 0; k < HH; k += 8) {
      half8 hv = *(const half8*)(hrow + k);
      #pragma unroll
      for (int i = 0; i < 8; ++i) sum += (float)hv[i] * wr[k + i];
    }
    out[b * 2 + c] = fmaxf(sum, 0.f);
  }
}

extern "C" void kernel_launch(void* const* d_in, const int* in_sizes, int n_in,
                              void* d_out, int out_size, void* d_ws, size_t ws_size,
                              hipStream_t stream) {
  const float* x    = (const float*)d_in[0];
  // d_in[1] = mask (unused by the model)
  const float* Wih0 = (const float*)d_in[2];
  const float* Whh0 = (const float*)d_in[3];
  const float* bi0  = (const float*)d_in[4];
  const float* bh0  = (const float*)d_in[5];
  const float* Wih1 = (const float*)d_in[6];
  const float* Whh1 = (const float*)d_in[7];
  const float* bi1  = (const float*)d_in[8];
  const float* bh1  = (const float*)d_in[9];
  const float* W2   = (const float*)d_in[10];
  const float* b2   = (const float*)d_in[11];
  _Float16* ws = (_Float16*)d_ws;
  unsigned* cnts = (unsigned*)((char*)d_ws + CNT_OFF);
  float* out   = (float*)d_out;

  // zero the barrier counters (d_ws is re-poisoned to 0xAA before every launch)
  (void)hipMemsetAsync((void*)cnts, 0, 8192, stream);

  const unsigned lds_bytes = (unsigned)(LDS_ELEMS * sizeof(_Float16));  // 112 KiB
  (void)hipFuncSetAttribute((const void*)rnn_fused,
                            hipFuncAttributeMaxDynamicSharedMemorySize,
                            (int)lds_bytes);

  void* args[] = { (void*)&x,
                   (void*)&Wih0, (void*)&Whh0, (void*)&bi0, (void*)&bh0,
                   (void*)&Wih1, (void*)&Whh1, (void*)&bi1, (void*)&bh1,
                   (void*)&W2,   (void*)&b2,   (void*)&ws,  (void*)&cnts,
                   (void*)&out };
  (void)hipLaunchCooperativeKernel((const void*)rnn_fused,
                                   dim3(256), dim3(256),
                                   args, lds_bytes, stream);
}

// Round 4
// 8414.392 us; speedup vs baseline: 5.4228x; 1.2727x over previous
//
#include <hip/hip_runtime.h>

typedef _Float16 half8 __attribute__((ext_vector_type(8)));
typedef float f32x4 __attribute__((ext_vector_type(4)));

constexpr int BB = 128;   // batch
constexpr int SS = 512;   // seq len
constexpr int II = 512;   // input dim
constexpr int HH = 1024;  // hidden dim

constexpr int JSL = 16;          // output-j's per WG (both layers)
constexpr int K0  = II + HH;     // layer-0 reduction: x(512) + h1(1024)
constexpr int K1  = HH + HH;     // layer-1 reduction: h1 + h2
constexpr int LDS_ELEMS = JSL * K0 + JSL * K1;   // 57344 fp16 = 112 KiB

constexpr size_t H_BYTES = (size_t)BB * HH * sizeof(_Float16);  // 256 KiB
constexpr size_t CNT_OFF = 4 * H_BYTES;                          // 1 MiB

__device__ inline float fast_tanh(float x) {
  float e = __expf(2.f * x);          // saturates to +-1 correctly at |x| large
  return 1.f - 2.f / (e + 1.f);
}
// Physical XCD id (HW_REG_XCC_ID = 20, offset 0, width 32) [measured: m09]
__device__ inline unsigned read_xcc() {
  return __builtin_amdgcn_s_getreg((31u << 11) | 20u) & 7u;
}

// Grid: 256 WGs (1 per CU, forced by 112 KiB LDS). bs = wg&3, js = wg>>2.
// 4 waves/WG: wave 0/1 layer-0 b-half 0/1; wave 2/3 layer-1 b-half 0/1.
// Weights fp16 in LDS (XOR-swizzled). h1/h2 ping-pong in d_ws with ordinary
// cached accesses. Per-step FULL-GRID barrier, hierarchical:
//   arrive:  leader fetch_add xarr[xcc] @ LLC (relaxed)
//   flusher: last arriver per XCD -> fence(release,agent) [ONE wbl2/XCD]
//            -> fetch_add gcnt @ LLC -> spin gcnt==8(t+1)
//            -> fence(acquire,agent) [ONE buffer_inv/XCD] -> bump xrel[xcc]
//   others:  spin xrel[xcc] >= t+1  (no cache maintenance at all)
// This cuts L2 cache-walks from 64/XCD/step (round 3) to 2/XCD/step.
__global__ __launch_bounds__(256, 1) void rnn_fused(
    const float* __restrict__ x,
    const float* __restrict__ Wih0, const float* __restrict__ Whh0,
    const float* __restrict__ bi0,  const float* __restrict__ bh0,
    const float* __restrict__ Wih1, const float* __restrict__ Whh1,
    const float* __restrict__ bi1,  const float* __restrict__ bh1,
    const float* __restrict__ W2,   const float* __restrict__ b2,
    _Float16* __restrict__ ws, unsigned* __restrict__ cnts,
    float* __restrict__ out)
{
  extern __shared__ _Float16 lds[];
  const int tid = threadIdx.x;
  const int wg  = blockIdx.x;
  const int bs  = wg & 3;        // batch-slice (perf heuristic: one per XCD under %8 RR)
  const int js  = wg >> 2;       // 64 j-slices
  const int j0  = js * JSL;
  const int Bb  = bs * 32;

  // ---- one-time: stage weight slices into LDS (fp16, swizzled) ----
  for (int e = tid; e < JSL * (K0 + K1); e += 256) {
    int jj = e / (K0 + K1);
    int kk = e - jj * (K0 + K1);
    float v; int dst;
    if (kk < K0) {
      v = (kk < II) ? Wih0[(size_t)(j0 + jj) * II + kk]
                    : Whh0[(size_t)(j0 + jj) * HH + (kk - II)];
      dst = jj * K0 + (kk ^ ((jj & 7) << 3));
    } else {
      int k2 = kk - K0;
      v = (k2 < HH) ? Wih1[(size_t)(j0 + jj) * HH + k2]
                    : Whh1[(size_t)(j0 + jj) * HH + (k2 - HH)];
      dst = JSL * K0 + jj * K1 + (k2 ^ ((jj & 7) << 3));
    }
    lds[dst] = (_Float16)v;
  }
  __syncthreads();

  const int wid   = tid >> 6;
  const int ln    = tid & 63;
  const int lj    = ln & 15;
  const int lk    = (ln >> 4) * 8;
  const int layer = wid >> 1;
  const int wb    = Bb + (wid & 1) * 16;
  const int arow  = wb + lj;
  const int swz   = (lj & 7) << 3;
  const unsigned xid = read_xcc();

  const float bias_f = (layer == 0) ? (bi0[j0 + lj] + bh0[j0 + lj])
                                    : (bi1[j0 + lj] + bh1[j0 + lj]);

  const _Float16* w0row = lds + lj * K0;
  const _Float16* w1row = lds + JSL * K0 + lj * K1;

  _Float16* h1A = ws;
  _Float16* h1B = ws + (size_t)BB * HH;
  _Float16* h2A = ws + (size_t)2 * BB * HH;
  _Float16* h2B = ws + (size_t)3 * BB * HH;
  _Float16 *h1p = h1A, *h1c = h1B, *h2p = h2A, *h2c = h2B;

  unsigned* xarr = cnts + xid * 32;          // per-XCD arrival counters (128B apart)
  unsigned* xrel = cnts + 512 + xid * 32;    // per-XCD release flags
  unsigned* gcnt = cnts + 1024;              // global flusher counter

  // x-projection for t=0 (no h dependency)
  f32x4 accx = {0.f, 0.f, 0.f, 0.f};
  if (layer == 0) {
    const float* xrow = x + ((size_t)arow * SS + 0) * II;
    #pragma unroll 8
    for (int kt = 0; kt < II / 32; ++kt) {
      int k = kt * 32 + lk;
      f32x4 u = *(const f32x4*)(xrow + k);
      f32x4 v = *(const f32x4*)(xrow + k + 4);
      half8 a;
      a[0]=(_Float16)u[0]; a[1]=(_Float16)u[1]; a[2]=(_Float16)u[2]; a[3]=(_Float16)u[3];
      a[4]=(_Float16)v[0]; a[5]=(_Float16)v[1]; a[6]=(_Float16)v[2]; a[7]=(_Float16)v[3];
      half8 b = *(const half8*)(w0row + (k ^ swz));
      accx = __builtin_amdgcn_mfma_f32_16x16x32_f16(a, b, accx, 0, 0, 0);
    }
  }

  // Pipelined scan: iteration t computes h1[t] (layer 0) and h2[t-1] (layer 1).
  for (int t = 0; t <= SS; ++t) {
    if (layer == 0) {
      if (t < SS) {
        f32x4 acc = accx;
        if (t > 0) {
          const _Float16* hrow = h1p + (size_t)arow * HH;
          half8 af[32];
          #pragma unroll
          for (int kt = 0; kt < 32; ++kt) af[kt] = *(const half8*)(hrow + kt * 32 + lk);
          #pragma unroll
          for (int kt = 0; kt < 32; ++kt) {
            int k = kt * 32 + lk;
            half8 b = *(const half8*)(w0row + ((II + k) ^ swz));
            acc = __builtin_amdgcn_mfma_f32_16x16x32_f16(af[kt], b, acc, 0, 0, 0);
          }
        }
        #pragma unroll
        for (int i = 0; i < 4; ++i) {
          int r = wb + (ln >> 4) * 4 + i;
          h1c[(size_t)r * HH + j0 + lj] = (_Float16)fast_tanh(acc[i] + bias_f);
        }
      }
    } else {
      if (t >= 1) {
        f32x4 acc = {0.f, 0.f, 0.f, 0.f};
        {
          const _Float16* hrow = h1p + (size_t)arow * HH;
          half8 af[32];
          #pragma unroll
          for (int kt = 0; kt < 32; ++kt) af[kt] = *(const half8*)(hrow + kt * 32 + lk);
          #pragma unroll
          for (int kt = 0; kt < 32; ++kt) {
            int k = kt * 32 + lk;
            half8 b = *(const half8*)(w1row + (k ^ swz));
            acc = __builtin_amdgcn_mfma_f32_16x16x32_f16(af[kt], b, acc, 0, 0, 0);
          }
        }
        if (t >= 2) {
          const _Float16* h2row = h2p + (size_t)arow * HH;
          half8 af[32];
          #pragma unroll
          for (int kt = 0; kt < 32; ++kt) af[kt] = *(const half8*)(h2row + kt * 32 + lk);
          #pragma unroll
          for (int kt = 0; kt < 32; ++kt) {
            int k = kt * 32 + lk;
            half8 b = *(const half8*)(w1row + ((HH + k) ^ swz));
            acc = __builtin_amdgcn_mfma_f32_16x16x32_f16(af[kt], b, acc, 0, 0, 0);
          }
        }
        #pragma unroll
        for (int i = 0; i < 4; ++i) {
          int r = wb + (ln >> 4) * 4 + i;
          h2c[(size_t)r * HH + j0 + lj] = (_Float16)fast_tanh(acc[i] + bias_f);
        }
      }
    }

    // ---- hierarchical full-grid barrier ----
    __syncthreads();                 // all 4 waves' h stores ACKed in local L2
    const unsigned tp1 = (unsigned)(t + 1);
    bool flusher = false;
    if (tid == 0) {
      unsigned old = __hip_atomic_fetch_add(xarr, 1u, __ATOMIC_RELAXED,
                                            __HIP_MEMORY_SCOPE_AGENT);
      flusher = (old == 32u * tp1 - 1u);     // last of this XCD's 32 WGs
      if (flusher) {
        __builtin_amdgcn_fence(__ATOMIC_RELEASE, "agent");  // ONE wbl2 per XCD
        __hip_atomic_fetch_add(gcnt, 1u, __ATOMIC_RELAXED,
                               __HIP_MEMORY_SCOPE_AGENT);
      }
    }

    // overlap next step's x-projection with barrier latency (reads immutable x)
    if (layer == 0 && (t + 1) < SS) {
      const float* xrow = x + ((size_t)arow * SS + (t + 1)) * II;
      f32x4 a2 = {0.f, 0.f, 0.f, 0.f};
      #pragma unroll 8
      for (int kt = 0; kt < II / 32; ++kt) {
        int k = kt * 32 + lk;
        f32x4 u = *(const f32x4*)(xrow + k);
        f32x4 v = *(const f32x4*)(xrow + k + 4);
        half8 a;
        a[0]=(_Float16)u[0]; a[1]=(_Float16)u[1]; a[2]=(_Float16)u[2]; a[3]=(_Float16)u[3];
        a[4]=(_Float16)v[0]; a[5]=(_Float16)v[1]; a[6]=(_Float16)v[2]; a[7]=(_Float16)v[3];
        half8 b = *(const half8*)(w0row + (k ^ swz));
        a2 = __builtin_amdgcn_mfma_f32_16x16x32_f16(a, b, a2, 0, 0, 0);
      }
      accx = a2;
    }

    if (tid == 0) {
      if (flusher) {
        while (__hip_atomic_load(gcnt, __ATOMIC_RELAXED,
                                 __HIP_MEMORY_SCOPE_AGENT) < 8u * tp1) {}
        __builtin_amdgcn_fence(__ATOMIC_ACQUIRE, "agent");  // ONE inv per XCD
        __hip_atomic_fetch_add(xrel, 1u, __ATOMIC_RELAXED,
                               __HIP_MEMORY_SCOPE_AGENT);
      } else {
        while (__hip_atomic_load(xrel, __ATOMIC_RELAXED,
                                 __HIP_MEMORY_SCOPE_AGENT) < tp1) {}
      }
    }
    __syncthreads();                 // WG proceeds only after XCD L2 is fresh

    _Float16* tt = h1p; h1p = h1c; h1c = tt;
    tt = h2p; h2p = h2c; h2c = tt;
  }

  // ---- FC head on WG 0 (final loop barrier already released h2 globally) ----
  if (wg == 0) {
    const int b = tid >> 1, c = tid & 1;
    const _Float16* hrow = h2p + (size_t)b * HH;
    const float* wr = W2 + (size_t)c * HH;
    float sum = b2[c];
    #pragma unroll 4
    for (int k = 0; k < HH; k += 8) {
      half8 hv = *(const half8*)(hrow + k);
      #pragma unroll
      for (int i = 0; i < 8; ++i) sum += (float)hv[i] * wr[k + i];
    }
    out[b * 2 + c] = fmaxf(sum, 0.f);
  }
}

extern "C" void kernel_launch(void* const* d_in, const int* in_sizes, int n_in,
                              void* d_out, int out_size, void* d_ws, size_t ws_size,
                              hipStream_t stream) {
  const float* x    = (const float*)d_in[0];
  // d_in[1] = mask (unused by the model)
  const float* Wih0 = (const float*)d_in[2];
  const float* Whh0 = (const float*)d_in[3];
  const float* bi0  = (const float*)d_in[4];
  const float* bh0  = (const float*)d_in[5];
  const float* Wih1 = (const float*)d_in[6];
  const float* Whh1 = (const float*)d_in[7];
  const float* bi1  = (const float*)d_in[8];
  const float* bh1  = (const float*)d_in[9];
  const float* W2   = (const float*)d_in[10];
  const float* b2   = (const float*)d_in[11];
  _Float16* ws = (_Float16*)d_ws;
  unsigned* cnts = (unsigned*)((char*)d_ws + CNT_OFF);
  float* out   = (float*)d_out;

  // zero the barrier counters (d_ws is re-poisoned to 0xAA before every launch)
  (void)hipMemsetAsync((void*)cnts, 0, 8192, stream);

  const unsigned lds_bytes = (unsigned)(LDS_ELEMS * sizeof(_Float16));  // 112 KiB
  (void)hipFuncSetAttribute((const void*)rnn_fused,
                            hipFuncAttributeMaxDynamicSharedMemorySize,
                            (int)lds_bytes);

  void* args[] = { (void*)&x,
                   (void*)&Wih0, (void*)&Whh0, (void*)&bi0, (void*)&bh0,
                   (void*)&Wih1, (void*)&Whh1, (void*)&bi1, (void*)&bh1,
                   (void*)&W2,   (void*)&b2,   (void*)&ws,  (void*)&cnts,
                   (void*)&out };
  (void)hipLaunchCooperativeKernel((const void*)rnn_fused,
                                   dim3(256), dim3(256),
                                   args, lds_bytes, stream);
}